// Round 10
// baseline (126.842 us; speedup 1.0000x reference)
//
#include <hip/hip_runtime.h>
#include <math.h>

// Problem constants
#define BATCH 1024
#define FEAT  512
#define NT    64
#define DDIM  1024          // CSETSIZE(64) * Nrf(4) * Nrf(4)

typedef __attribute__((ext_vector_type(8))) short  short8;
typedef __attribute__((ext_vector_type(4))) float  floatx4;

// ws layout (bytes):
//   A-image : 16 row-tiles x 8 k-tiles x 8 KB = 1,048,576
//   B-image : 32 col-tiles x 8 k-tiles x 8 KB = 2,097,152 (Dr/Di interleaved)
#define AIMG_OFF  0
#define BIMG_OFF  1048576

// fp32 -> bf16 round-to-nearest-even
__device__ __forceinline__ unsigned short bf16rne(float f) {
    unsigned int u = __float_as_uint(f);
    return (unsigned short)((u + 0x7fffu + ((u >> 16) & 1u)) >> 16);
}

__device__ __forceinline__ void gld16(const unsigned char* g, unsigned char* l) {
    __builtin_amdgcn_global_load_lds(
        (const __attribute__((address_space(1))) unsigned int*)g,
        (__attribute__((address_space(3))) unsigned int*)l, 16, 0, 0);
}

// Output layout (flat):
//   A_real : [0, BATCH*4096)   A_imag : [BATCH*4096, 2*BATCH*4096)
//   D_r_n  : 2*BATCH*4096 + [0, BATCH*1024)
//   D_i_n  : 2*BATCH*4096 + BATCH*1024 + [0, BATCH*1024)
//   CSet   : last 16384 floats

// ===========================================================================
// K0: uniform prep (r9-verified).
//  bid<256:      convert fp32 -> bf16 LDS-image tiles (8 KB = 64 rows x 64 k,
//                16B chunks XOR-swizzled c^(r&7)). B-image interleaves Dr/Di
//                per 16-col c-block.
//  bid 256..271: CSet pass-through.
// ===========================================================================
__global__ __launch_bounds__(256) void k0_prep(
    const float* __restrict__ x,
    const float* __restrict__ W_Dr, const float* __restrict__ W_Di,
    const float* __restrict__ cset,
    unsigned char* __restrict__ ws, float* __restrict__ out)
{
    const int bid = blockIdx.x;
    const int tid = threadIdx.x;

    if (bid < 256) {
        unsigned short* aimg = (unsigned short*)(ws + AIMG_OFF);
        unsigned short* bimg = (unsigned short*)(ws + BIMG_OFF);
        const int gtid = bid * 256 + tid;   // 65536 threads
        for (int idx = gtid; idx < 196608; idx += 65536) {
            const float* src;
            unsigned short* dst;
            if (idx < 65536) {                 // A-image: x
                const int rt = idx >> 12, kb = (idx >> 9) & 7;
                const int r  = (idx >> 3) & 63, c = idx & 7;
                src = x + ((size_t)(rt * 64 + r) * FEAT + kb * 64 + c * 8);
                dst = aimg + ((rt * 8 + kb) * 4096 + r * 64 + ((c ^ (r & 7)) * 8));
            } else {                           // B-image: W_Dr/W_Di interleaved
                const int j  = idx - 65536;
                const int ct = j >> 12, kb = (j >> 9) & 7;
                const int n  = (j >> 3) & 63, c = j & 7;
                const int g = n >> 5, h = (n >> 4) & 1, pos = n & 15;
                const float* wrow =
                    (h ? W_Di : W_Dr) + (size_t)(ct * 32 + g * 16 + pos) * FEAT;
                src = wrow + kb * 64 + c * 8;
                dst = bimg + ((ct * 8 + kb) * 4096 + n * 64 + ((c ^ (n & 7)) * 8));
            }
            const float4 v0 = *(const float4*)src;
            const float4 v1 = *(const float4*)(src + 4);
            short8 o;
            o[0] = (short)bf16rne(v0.x); o[1] = (short)bf16rne(v0.y);
            o[2] = (short)bf16rne(v0.z); o[3] = (short)bf16rne(v0.w);
            o[4] = (short)bf16rne(v1.x); o[5] = (short)bf16rne(v1.y);
            o[6] = (short)bf16rne(v1.z); o[7] = (short)bf16rne(v1.w);
            *(short8*)dst = o;
        }
    } else {
        const int cb = bid - 256;              // 0..15
        const size_t base = (size_t)2 * BATCH * 4096 + (size_t)2 * BATCH * DDIM;
        ((float4*)(out + base))[cb * 256 + tid] = ((const float4*)cset)[cb * 256 + tid];
    }
}

// ===========================================================================
// K1: uniform 512-block D-GEMM from images (r7/r8/r9-verified path).
//  rt=bid&15, ct=bid>>4 (0..31). global_load_lds double-buffered,
//  1 barrier/64-K step; bias + per-row Frobenius norm epilogue, 2*D/V_F.
// ===========================================================================
__global__ __launch_bounds__(256) void k1_gemm(
    const unsigned char* __restrict__ ws,
    const float* __restrict__ b_Dr, const float* __restrict__ b_Di,
    float* __restrict__ out)
{
    __shared__ __align__(16) unsigned char smem[32768];

    const int bid  = blockIdx.x;
    const int tid  = threadIdx.x;
    const int rt   = bid & 15;
    const int ct   = bid >> 4;        // 0..31
    const int lane = tid & 63;
    const int wv   = tid >> 6;
    const int ln   = lane & 15;
    const int quad = lane >> 4;
    const int row0 = rt * 64;

    const unsigned char* Atiles = ws + AIMG_OFF + (size_t)rt * 8 * 8192;
    const unsigned char* Btiles = ws + BIMG_OFF + (size_t)ct * 8 * 8192;

    const int g0 = (wv * 2 + 0) * 1024;
    const int g1 = (wv * 2 + 1) * 1024;
    const int lo = lane * 16;

    floatx4 acc[4] = {{0,0,0,0},{0,0,0,0},{0,0,0,0},{0,0,0,0}};

    {   // prefetch kb=0 into buf 0
        unsigned char* La = smem;
        unsigned char* Lb = smem + 8192;
        gld16(Atiles + g0 + lo, La + g0);
        gld16(Atiles + g1 + lo, La + g1);
        gld16(Btiles + g0 + lo, Lb + g0);
        gld16(Btiles + g1 + lo, Lb + g1);
    }

    const int rowOffA = (wv * 16 + ln) * 128;
    const int swz = ln & 7;
    int cur = 0;

    #pragma unroll 1
    for (int kb = 0; kb < 8; ++kb) {
        __syncthreads();   // buf 'cur' staged (vmcnt drain); prev reads done
        if (kb < 7) {
            const unsigned char* At = Atiles + (kb + 1) * 8192;
            const unsigned char* Bt = Btiles + (kb + 1) * 8192;
            unsigned char* La = smem + (cur ^ 1) * 16384;
            unsigned char* Lb = La + 8192;
            gld16(At + g0 + lo, La + g0);
            gld16(At + g1 + lo, La + g1);
            gld16(Bt + g0 + lo, Lb + g0);
            gld16(Bt + g1 + lo, Lb + g1);
        }
        const unsigned char* La = smem + cur * 16384;
        const unsigned char* Lb = La + 8192;
        #pragma unroll
        for (int ks = 0; ks < 2; ++ks) {
            const int ca = ((ks * 4 + quad) ^ swz) * 16;
            const short8 a = *(const short8*)(La + rowOffA + ca);
            #pragma unroll
            for (int t = 0; t < 4; ++t) {
                const short8 b = *(const short8*)(Lb + (t * 16 + ln) * 128 + ca);
                acc[t] = __builtin_amdgcn_mfma_f32_16x16x32_bf16(a, b, acc[t], 0, 0, 0);
            }
        }
        cur ^= 1;
    }

    // epilogue: bias + per-row Frobenius norm (C/D: col=lane&15, row=quad*4+i)
    const size_t drn = (size_t)2 * BATCH * 4096;
    const size_t din = drn + (size_t)BATCH * DDIM;
    const int woff = ct * 32;
    #pragma unroll
    for (int p = 0; p < 2; ++p) {
        const int colg = woff + p * 16 + ln;
        const float br = b_Dr[colg];
        const float bi = b_Di[colg];
        float dr[4], di[4], ps[4];
        #pragma unroll
        for (int i = 0; i < 4; ++i) {
            dr[i] = acc[2 * p][i] + br;
            di[i] = acc[2 * p + 1][i] + bi;
            ps[i] = dr[i] * dr[i] + di[i] * di[i];
        }
        #pragma unroll
        for (int i = 0; i < 4; ++i) {
            ps[i] += __shfl_xor(ps[i], 1);
            ps[i] += __shfl_xor(ps[i], 2);
            ps[i] += __shfl_xor(ps[i], 4);
            ps[i] += __shfl_xor(ps[i], 8);
        }
        #pragma unroll
        for (int i = 0; i < 4; ++i) {
            const float scale = 2.0f / sqrtf(8.0f * ps[i]);
            const size_t row_g = (size_t)(row0 + wv * 16 + quad * 4 + i);
            out[drn + row_g * DDIM + colg] = dr[i] * scale;
            out[din + row_g * DDIM + colg] = di[i] * scale;
        }
    }
}

// ===========================================================================
// K2: A_real/A_imag fill, 1024 blocks (b = bid), in-block theta (r9-verified):
//  thread (t=tid>>2, q=tid&3) dots x[b]·W_A[t] over its k-quarter (32 float4
//  pairs chunked 8-deep), shfl-quad reduce, sincos at q==0 -> LDS, one
//  barrier, then 32 KB of diagonal-matrix stores. No ws dependency.
// ===========================================================================
__global__ __launch_bounds__(256) void k2_fill(
    const float* __restrict__ x, const float* __restrict__ W_A,
    const float* __restrict__ b_A,
    float* __restrict__ out)
{
    __shared__ float cosT[NT], sinT[NT];
    const int b   = blockIdx.x;
    const int tid = threadIdx.x;
    const int t   = tid >> 2;          // antenna 0..63
    const int q   = tid & 3;           // k-quarter phase

    const float* wrow = W_A + (size_t)t * FEAT + q * 4;
    const float* xrow = x   + (size_t)b * FEAT + q * 4;
    float sum = 0.f;
    #pragma unroll 1
    for (int ch = 0; ch < 4; ++ch) {       // 4 chunks x 8 float4-pairs
        float4 wv4[8], xv4[8];
        #pragma unroll
        for (int i = 0; i < 8; ++i) {
            const int ko = (ch * 8 + i) * 16;
            wv4[i] = *(const float4*)(wrow + ko);
            xv4[i] = *(const float4*)(xrow + ko);
        }
        #pragma unroll
        for (int i = 0; i < 8; ++i)
            sum += wv4[i].x * xv4[i].x + wv4[i].y * xv4[i].y
                 + wv4[i].z * xv4[i].z + wv4[i].w * xv4[i].w;
    }
    sum += __shfl_xor(sum, 1);
    sum += __shfl_xor(sum, 2);             // quad now holds full dot
    if (q == 0) {
        float s, c;
        sincosf(sum + b_A[t], &s, &c);
        cosT[t] = c; sinT[t] = s;
    }
    __syncthreads();

    float* ar = out + (size_t)b * 4096;
    float* ai = out + (size_t)BATCH * 4096 + (size_t)b * 4096;
    #pragma unroll
    for (int it = 0; it < 4; ++it) {
        const int idx = tid + it * 256;   // float4 chunk 0..1023
        const int tt = idx >> 4;          // row in 64x64
        const int j0 = (idx & 15) * 4;    // first col of chunk
        float4 vr = {0.f, 0.f, 0.f, 0.f};
        float4 vi = {0.f, 0.f, 0.f, 0.f};
        if (tt >= j0 && tt < j0 + 4) {
            ((float*)&vr)[tt - j0] = cosT[tt];
            ((float*)&vi)[tt - j0] = sinT[tt];
        }
        ((float4*)ar)[idx] = vr;
        ((float4*)ai)[idx] = vi;
    }
}

extern "C" void kernel_launch(void* const* d_in, const int* in_sizes, int n_in,
                              void* d_out, int out_size, void* d_ws, size_t ws_size,
                              hipStream_t stream) {
    const float* x    = (const float*)d_in[0];
    const float* W_A  = (const float*)d_in[1];
    const float* b_A  = (const float*)d_in[2];
    const float* W_Dr = (const float*)d_in[3];
    const float* b_Dr = (const float*)d_in[4];
    const float* W_Di = (const float*)d_in[5];
    const float* b_Di = (const float*)d_in[6];
    const float* CSet = (const float*)d_in[7];
    float* out = (float*)d_out;
    unsigned char* ws = (unsigned char*)d_ws;

    k0_prep<<<272, 256, 0, stream>>>(x, W_Dr, W_Di, CSet, ws, out);
    k1_gemm<<<512, 256, 0, stream>>>(ws, b_Dr, b_Di, out);
    k2_fill<<<1024, 256, 0, stream>>>(x, W_A, b_A, out);
}

// Round 11
// 122.563 us; speedup vs baseline: 1.0349x; 1.0349x over previous
//
#include <hip/hip_runtime.h>
#include <math.h>

// Problem constants
#define BATCH 1024
#define FEAT  512
#define NT    64
#define DDIM  1024          // CSETSIZE(64) * Nrf(4) * Nrf(4)

typedef __attribute__((ext_vector_type(8))) short  short8;
typedef __attribute__((ext_vector_type(4))) float  floatx4;

// ws layout (bytes):
//   A-image : 16 row-tiles x 8 k-tiles x 8 KB = 1,048,576
//   B-image : 32 col-tiles x 8 k-tiles x 8 KB = 2,097,152 (Dr/Di interleaved)
#define AIMG_OFF  0
#define BIMG_OFF  1048576

// fp32 -> bf16 round-to-nearest-even
__device__ __forceinline__ unsigned short bf16rne(float f) {
    unsigned int u = __float_as_uint(f);
    return (unsigned short)((u + 0x7fffu + ((u >> 16) & 1u)) >> 16);
}

__device__ __forceinline__ void gld16(const unsigned char* g, unsigned char* l) {
    __builtin_amdgcn_global_load_lds(
        (const __attribute__((address_space(1))) unsigned int*)g,
        (__attribute__((address_space(3))) unsigned int*)l, 16, 0, 0);
}

// Output layout (flat):
//   A_real : [0, BATCH*4096)   A_imag : [BATCH*4096, 2*BATCH*4096)
//   D_r_n  : 2*BATCH*4096 + [0, BATCH*1024)
//   D_i_n  : 2*BATCH*4096 + BATCH*1024 + [0, BATCH*1024)
//   CSet   : last 16384 floats

// ===========================================================================
// K0 (launch 1, 1296 blocks) — all GEMM-independent work, mutually parallel:
//  bid<256:        convert fp32 -> bf16 LDS-image tiles (8 KB = 64 rows x 64 k,
//                  16B chunks XOR-swizzled c^(r&7)); B-image interleaves Dr/Di
//                  per 16-col c-block.                      (r9-verified)
//  bid 256..1279:  A_real/A_imag fill for b = bid-256 with IN-BLOCK theta:
//                  thread (t=tid>>2,q=tid&3) dots x[b]·W_A[t] over its
//                  k-quarter, shfl-quad reduce, sincos -> LDS, one barrier,
//                  32 KB diagonal stores.                   (r9-verified)
//  bid 1280..1295: CSet pass-through.
// ===========================================================================
__global__ __launch_bounds__(256) void k0_prep(
    const float* __restrict__ x,
    const float* __restrict__ W_A,  const float* __restrict__ b_A,
    const float* __restrict__ W_Dr, const float* __restrict__ W_Di,
    const float* __restrict__ cset,
    unsigned char* __restrict__ ws, float* __restrict__ out)
{
    __shared__ float cosT[NT], sinT[NT];
    const int bid = blockIdx.x;
    const int tid = threadIdx.x;

    if (bid < 256) {
        // ---------------- convert path ----------------
        unsigned short* aimg = (unsigned short*)(ws + AIMG_OFF);
        unsigned short* bimg = (unsigned short*)(ws + BIMG_OFF);
        const int gtid = bid * 256 + tid;   // 65536 threads
        for (int idx = gtid; idx < 196608; idx += 65536) {
            const float* src;
            unsigned short* dst;
            if (idx < 65536) {                 // A-image: x
                const int rt = idx >> 12, kb = (idx >> 9) & 7;
                const int r  = (idx >> 3) & 63, c = idx & 7;
                src = x + ((size_t)(rt * 64 + r) * FEAT + kb * 64 + c * 8);
                dst = aimg + ((rt * 8 + kb) * 4096 + r * 64 + ((c ^ (r & 7)) * 8));
            } else {                           // B-image: W_Dr/W_Di interleaved
                const int j  = idx - 65536;
                const int ct = j >> 12, kb = (j >> 9) & 7;
                const int n  = (j >> 3) & 63, c = j & 7;
                const int g = n >> 5, h = (n >> 4) & 1, pos = n & 15;
                const float* wrow =
                    (h ? W_Di : W_Dr) + (size_t)(ct * 32 + g * 16 + pos) * FEAT;
                src = wrow + kb * 64 + c * 8;
                dst = bimg + ((ct * 8 + kb) * 4096 + n * 64 + ((c ^ (n & 7)) * 8));
            }
            const float4 v0 = *(const float4*)src;
            const float4 v1 = *(const float4*)(src + 4);
            short8 o;
            o[0] = (short)bf16rne(v0.x); o[1] = (short)bf16rne(v0.y);
            o[2] = (short)bf16rne(v0.z); o[3] = (short)bf16rne(v0.w);
            o[4] = (short)bf16rne(v1.x); o[5] = (short)bf16rne(v1.y);
            o[6] = (short)bf16rne(v1.z); o[7] = (short)bf16rne(v1.w);
            *(short8*)dst = o;
        }
    } else if (bid < 1280) {
        // ---------------- A-fill path (in-block theta) ----------------
        const int b = bid - 256;
        const int t = tid >> 2;          // antenna 0..63
        const int q = tid & 3;           // k-quarter phase

        const float* wrow = W_A + (size_t)t * FEAT + q * 4;
        const float* xrow = x   + (size_t)b * FEAT + q * 4;
        float sum = 0.f;
        #pragma unroll 1
        for (int ch = 0; ch < 4; ++ch) {       // 4 chunks x 8 float4-pairs
            float4 wv4[8], xv4[8];
            #pragma unroll
            for (int i = 0; i < 8; ++i) {
                const int ko = (ch * 8 + i) * 16;
                wv4[i] = *(const float4*)(wrow + ko);
                xv4[i] = *(const float4*)(xrow + ko);
            }
            #pragma unroll
            for (int i = 0; i < 8; ++i)
                sum += wv4[i].x * xv4[i].x + wv4[i].y * xv4[i].y
                     + wv4[i].z * xv4[i].z + wv4[i].w * xv4[i].w;
        }
        sum += __shfl_xor(sum, 1);
        sum += __shfl_xor(sum, 2);             // quad now holds full dot
        if (q == 0) {
            float s, c;
            sincosf(sum + b_A[t], &s, &c);
            cosT[t] = c; sinT[t] = s;
        }
        __syncthreads();

        float* ar = out + (size_t)b * 4096;
        float* ai = out + (size_t)BATCH * 4096 + (size_t)b * 4096;
        #pragma unroll
        for (int it = 0; it < 4; ++it) {
            const int idx = tid + it * 256;   // float4 chunk 0..1023
            const int tt = idx >> 4;          // row in 64x64
            const int j0 = (idx & 15) * 4;    // first col of chunk
            float4 vr = {0.f, 0.f, 0.f, 0.f};
            float4 vi = {0.f, 0.f, 0.f, 0.f};
            if (tt >= j0 && tt < j0 + 4) {
                ((float*)&vr)[tt - j0] = cosT[tt];
                ((float*)&vi)[tt - j0] = sinT[tt];
            }
            ((float4*)ar)[idx] = vr;
            ((float4*)ai)[idx] = vi;
        }
    } else {
        // ---------------- CSet pass-through ----------------
        const int cb = bid - 1280;             // 0..15
        const size_t base = (size_t)2 * BATCH * 4096 + (size_t)2 * BATCH * DDIM;
        ((float4*)(out + base))[cb * 256 + tid] = ((const float4*)cset)[cb * 256 + tid];
    }
}

// ===========================================================================
// K1 (launch 2, 512 blocks): uniform D-GEMM from images (r7-r10 verified).
//  rt=bid&15, ct=bid>>4 (0..31). global_load_lds double-buffered,
//  1 barrier/64-K step; bias + per-row Frobenius norm epilogue, 2*D/V_F.
// ===========================================================================
__global__ __launch_bounds__(256) void k1_gemm(
    const unsigned char* __restrict__ ws,
    const float* __restrict__ b_Dr, const float* __restrict__ b_Di,
    float* __restrict__ out)
{
    __shared__ __align__(16) unsigned char smem[32768];

    const int bid  = blockIdx.x;
    const int tid  = threadIdx.x;
    const int rt   = bid & 15;
    const int ct   = bid >> 4;        // 0..31
    const int lane = tid & 63;
    const int wv   = tid >> 6;
    const int ln   = lane & 15;
    const int quad = lane >> 4;
    const int row0 = rt * 64;

    const unsigned char* Atiles = ws + AIMG_OFF + (size_t)rt * 8 * 8192;
    const unsigned char* Btiles = ws + BIMG_OFF + (size_t)ct * 8 * 8192;

    const int g0 = (wv * 2 + 0) * 1024;
    const int g1 = (wv * 2 + 1) * 1024;
    const int lo = lane * 16;

    floatx4 acc[4] = {{0,0,0,0},{0,0,0,0},{0,0,0,0},{0,0,0,0}};

    {   // prefetch kb=0 into buf 0
        unsigned char* La = smem;
        unsigned char* Lb = smem + 8192;
        gld16(Atiles + g0 + lo, La + g0);
        gld16(Atiles + g1 + lo, La + g1);
        gld16(Btiles + g0 + lo, Lb + g0);
        gld16(Btiles + g1 + lo, Lb + g1);
    }

    const int rowOffA = (wv * 16 + ln) * 128;
    const int swz = ln & 7;
    int cur = 0;

    #pragma unroll 1
    for (int kb = 0; kb < 8; ++kb) {
        __syncthreads();   // buf 'cur' staged (vmcnt drain); prev reads done
        if (kb < 7) {
            const unsigned char* At = Atiles + (kb + 1) * 8192;
            const unsigned char* Bt = Btiles + (kb + 1) * 8192;
            unsigned char* La = smem + (cur ^ 1) * 16384;
            unsigned char* Lb = La + 8192;
            gld16(At + g0 + lo, La + g0);
            gld16(At + g1 + lo, La + g1);
            gld16(Bt + g0 + lo, Lb + g0);
            gld16(Bt + g1 + lo, Lb + g1);
        }
        const unsigned char* La = smem + cur * 16384;
        const unsigned char* Lb = La + 8192;
        #pragma unroll
        for (int ks = 0; ks < 2; ++ks) {
            const int ca = ((ks * 4 + quad) ^ swz) * 16;
            const short8 a = *(const short8*)(La + rowOffA + ca);
            #pragma unroll
            for (int t = 0; t < 4; ++t) {
                const short8 b = *(const short8*)(Lb + (t * 16 + ln) * 128 + ca);
                acc[t] = __builtin_amdgcn_mfma_f32_16x16x32_bf16(a, b, acc[t], 0, 0, 0);
            }
        }
        cur ^= 1;
    }

    // epilogue: bias + per-row Frobenius norm (C/D: col=lane&15, row=quad*4+i)
    const size_t drn = (size_t)2 * BATCH * 4096;
    const size_t din = drn + (size_t)BATCH * DDIM;
    const int woff = ct * 32;
    #pragma unroll
    for (int p = 0; p < 2; ++p) {
        const int colg = woff + p * 16 + ln;
        const float br = b_Dr[colg];
        const float bi = b_Di[colg];
        float dr[4], di[4], ps[4];
        #pragma unroll
        for (int i = 0; i < 4; ++i) {
            dr[i] = acc[2 * p][i] + br;
            di[i] = acc[2 * p + 1][i] + bi;
            ps[i] = dr[i] * dr[i] + di[i] * di[i];
        }
        #pragma unroll
        for (int i = 0; i < 4; ++i) {
            ps[i] += __shfl_xor(ps[i], 1);
            ps[i] += __shfl_xor(ps[i], 2);
            ps[i] += __shfl_xor(ps[i], 4);
            ps[i] += __shfl_xor(ps[i], 8);
        }
        #pragma unroll
        for (int i = 0; i < 4; ++i) {
            const float scale = 2.0f / sqrtf(8.0f * ps[i]);
            const size_t row_g = (size_t)(row0 + wv * 16 + quad * 4 + i);
            out[drn + row_g * DDIM + colg] = dr[i] * scale;
            out[din + row_g * DDIM + colg] = di[i] * scale;
        }
    }
}

extern "C" void kernel_launch(void* const* d_in, const int* in_sizes, int n_in,
                              void* d_out, int out_size, void* d_ws, size_t ws_size,
                              hipStream_t stream) {
    const float* x    = (const float*)d_in[0];
    const float* W_A  = (const float*)d_in[1];
    const float* b_A  = (const float*)d_in[2];
    const float* W_Dr = (const float*)d_in[3];
    const float* b_Dr = (const float*)d_in[4];
    const float* W_Di = (const float*)d_in[5];
    const float* b_Di = (const float*)d_in[6];
    const float* CSet = (const float*)d_in[7];
    float* out = (float*)d_out;
    unsigned char* ws = (unsigned char*)d_ws;

    k0_prep<<<1296, 256, 0, stream>>>(x, W_A, b_A, W_Dr, W_Di, CSet, ws, out);
    k1_gemm<<<512, 256, 0, stream>>>(ws, b_Dr, b_Di, out);
}

// Round 12
// 107.644 us; speedup vs baseline: 1.1784x; 1.1386x over previous
//
#include <hip/hip_runtime.h>
#include <math.h>

// Problem constants
#define BATCH 1024
#define FEAT  512
#define NT    64
#define DDIM  1024          // CSETSIZE(64) * Nrf(4) * Nrf(4)

typedef __attribute__((ext_vector_type(8))) short  short8;
typedef __attribute__((ext_vector_type(4))) short  short4v;
typedef __attribute__((ext_vector_type(4))) float  floatx4;

// ws layout (bytes):
//   A-image : 16 row-tiles x 8 k-tiles x 8 KB = 1,048,576
//   B-image : 32 col-tiles x 8 k-tiles x 8 KB = 2,097,152 (Dr/Di interleaved)
//   theta   : BATCH*NT fp32 at 3,276,800
#define AIMG_OFF  0
#define BIMG_OFF  1048576
#define THETA_OFF 3276800

// fp32 -> bf16 round-to-nearest-even
__device__ __forceinline__ unsigned short bf16rne(float f) {
    unsigned int u = __float_as_uint(f);
    return (unsigned short)((u + 0x7fffu + ((u >> 16) & 1u)) >> 16);
}
__device__ __forceinline__ short4v pack4(const float4 a) {
    short4v r;
    r[0] = (short)bf16rne(a.x); r[1] = (short)bf16rne(a.y);
    r[2] = (short)bf16rne(a.z); r[3] = (short)bf16rne(a.w);
    return r;
}

__device__ __forceinline__ void gld16(const unsigned char* g, unsigned char* l) {
    __builtin_amdgcn_global_load_lds(
        (const __attribute__((address_space(1))) unsigned int*)g,
        (__attribute__((address_space(3))) unsigned int*)l, 16, 0, 0);
}

// Output layout (flat):
//   A_real : [0, BATCH*4096)   A_imag : [BATCH*4096, 2*BATCH*4096)
//   D_r_n  : 2*BATCH*4096 + [0, BATCH*1024)
//   D_i_n  : 2*BATCH*4096 + BATCH*1024 + [0, BATCH*1024)
//   CSet   : last 16384 floats
// A_real/A_imag bulk zeros come from hipMemsetAsync; kernels only patch diag.

// ===========================================================================
// K0 (288 blocks) — r8-verified:
//  bid<256:      convert fp32 -> bf16 LDS-image tiles (8 KB = 64 rows x 64 k,
//                16B chunks XOR-swizzled c^(r&7)); B-image interleaves Dr/Di
//                per 16-col c-block.
//  bid 256..271: theta GEMM (64 b-rows x 64 antennas, direct fp32 + register
//                prefetch, MFMA bf16, COALESCED staging) -> theta_ws.
//  bid 272..287: CSet pass-through.
// ===========================================================================
__global__ __launch_bounds__(256) void k0_prep(
    const float* __restrict__ x,
    const float* __restrict__ W_A,  const float* __restrict__ b_A,
    const float* __restrict__ W_Dr, const float* __restrict__ W_Di,
    const float* __restrict__ cset,
    unsigned char* __restrict__ ws, float* __restrict__ out)
{
    __shared__ __align__(16) unsigned short As[64][40];
    __shared__ __align__(16) unsigned short Bs[64][40];

    const int bid = blockIdx.x;
    const int tid = threadIdx.x;

    if (bid < 256) {
        // ---------------- convert path ----------------
        unsigned short* aimg = (unsigned short*)(ws + AIMG_OFF);
        unsigned short* bimg = (unsigned short*)(ws + BIMG_OFF);
        const int gtid = bid * 256 + tid;   // 65536 threads
        for (int idx = gtid; idx < 196608; idx += 65536) {
            const float* src;
            unsigned short* dst;
            if (idx < 65536) {                 // A-image: x
                const int rt = idx >> 12, kb = (idx >> 9) & 7;
                const int r  = (idx >> 3) & 63, c = idx & 7;
                src = x + ((size_t)(rt * 64 + r) * FEAT + kb * 64 + c * 8);
                dst = aimg + ((rt * 8 + kb) * 4096 + r * 64 + ((c ^ (r & 7)) * 8));
            } else {                           // B-image: W_Dr/W_Di interleaved
                const int j  = idx - 65536;
                const int ct = j >> 12, kb = (j >> 9) & 7;
                const int n  = (j >> 3) & 63, c = j & 7;
                const int g = n >> 5, h = (n >> 4) & 1, pos = n & 15;
                const float* wrow =
                    (h ? W_Di : W_Dr) + (size_t)(ct * 32 + g * 16 + pos) * FEAT;
                src = wrow + kb * 64 + c * 8;
                dst = bimg + ((ct * 8 + kb) * 4096 + n * 64 + ((c ^ (n & 7)) * 8));
            }
            const float4 v0 = *(const float4*)src;
            const float4 v1 = *(const float4*)(src + 4);
            short8 o;
            o[0] = (short)bf16rne(v0.x); o[1] = (short)bf16rne(v0.y);
            o[2] = (short)bf16rne(v0.z); o[3] = (short)bf16rne(v0.w);
            o[4] = (short)bf16rne(v1.x); o[5] = (short)bf16rne(v1.y);
            o[6] = (short)bf16rne(v1.z); o[7] = (short)bf16rne(v1.w);
            *(short8*)dst = o;
        }
    } else if (bid < 272) {
        // ---------------- theta GEMM path (direct fp32, reg prefetch) --------
        float* theta_ws = (float*)(ws + THETA_OFF);
        const int lane = tid & 63;
        const int wv   = tid >> 6;
        const int ln   = lane & 15;
        const int quad = lane >> 4;
        const int f = tid & 7;
        const int r = tid >> 3;
        const int row0 = (bid - 256) * 64;

        const float* arow0 = x + (size_t)(row0 + r) * FEAT;
        const float* arow1 = x + (size_t)(row0 + r + 32) * FEAT;
        const float* brow0 = W_A + (size_t)r * FEAT;
        const float* brow1 = W_A + (size_t)(r + 32) * FEAT;

        float4 pa0 = *(const float4*)(arow0 + f * 4);
        float4 pa1 = *(const float4*)(arow1 + f * 4);
        float4 pb0 = *(const float4*)(brow0 + f * 4);
        float4 pb1 = *(const float4*)(brow1 + f * 4);

        floatx4 acc[4] = {{0,0,0,0},{0,0,0,0},{0,0,0,0},{0,0,0,0}};

        #pragma unroll 1
        for (int it = 0; it < 16; ++it) {
            __syncthreads();
            *(short4v*)&As[r][f * 4]      = pack4(pa0);
            *(short4v*)&As[r + 32][f * 4] = pack4(pa1);
            *(short4v*)&Bs[r][f * 4]      = pack4(pb0);
            *(short4v*)&Bs[r + 32][f * 4] = pack4(pb1);
            __syncthreads();
            if (it < 15) {
                const int ko = (it + 1) * 32 + f * 4;
                pa0 = *(const float4*)(arow0 + ko);
                pa1 = *(const float4*)(arow1 + ko);
                pb0 = *(const float4*)(brow0 + ko);
                pb1 = *(const float4*)(brow1 + ko);
            }
            const short8 a = *(const short8*)&As[wv * 16 + ln][quad * 8];
            #pragma unroll
            for (int t = 0; t < 4; ++t) {
                const short8 b = *(const short8*)&Bs[t * 16 + ln][quad * 8];
                acc[t] = __builtin_amdgcn_mfma_f32_16x16x32_bf16(a, b, acc[t], 0, 0, 0);
            }
        }
        // C/D layout: col = lane&15, row = quad*4 + reg
        #pragma unroll
        for (int t = 0; t < 4; ++t) {
            const int colg = t * 16 + ln;
            const float ba = b_A[colg];
            #pragma unroll
            for (int i = 0; i < 4; ++i) {
                const int row_g = row0 + wv * 16 + quad * 4 + i;
                theta_ws[row_g * NT + colg] = acc[t][i] + ba;
            }
        }
    } else {
        // ---------------- CSet pass-through ----------------
        const int cb = bid - 272;              // 0..15
        const size_t base = (size_t)2 * BATCH * 4096 + (size_t)2 * BATCH * DDIM;
        ((float4*)(out + base))[cb * 256 + tid] = ((const float4*)cset)[cb * 256 + tid];
    }
}

// ===========================================================================
// K1 (544 blocks):
//  bid<512:       uniform D-GEMM from images (r7-r11 verified). rt=bid&15,
//                 ct=bid>>4. global_load_lds double-buffered, 1 barrier/step;
//                 bias + per-row Frobenius norm epilogue, 2*D/V_F.
//  bid 512..543:  diagonal patch: thread (b=pb*32+(tid>>3), tgrp=tid&7)
//                 reads 8 thetas, sincos, stores cos/sin at out[b*4096+t*65]
//                 (+A_imag base). Runs after the memset in stream order.
// ===========================================================================
__global__ __launch_bounds__(256) void k1_main(
    const unsigned char* __restrict__ ws,
    const float* __restrict__ b_Dr, const float* __restrict__ b_Di,
    float* __restrict__ out)
{
    __shared__ __align__(16) unsigned char smem[32768];

    const int bid = blockIdx.x;
    const int tid = threadIdx.x;

    if (bid < 512) {
        const int rt   = bid & 15;
        const int ct   = bid >> 4;        // 0..31
        const int lane = tid & 63;
        const int wv   = tid >> 6;
        const int ln   = lane & 15;
        const int quad = lane >> 4;
        const int row0 = rt * 64;

        const unsigned char* Atiles = ws + AIMG_OFF + (size_t)rt * 8 * 8192;
        const unsigned char* Btiles = ws + BIMG_OFF + (size_t)ct * 8 * 8192;

        const int g0 = (wv * 2 + 0) * 1024;
        const int g1 = (wv * 2 + 1) * 1024;
        const int lo = lane * 16;

        floatx4 acc[4] = {{0,0,0,0},{0,0,0,0},{0,0,0,0},{0,0,0,0}};

        {   // prefetch kb=0 into buf 0
            unsigned char* La = smem;
            unsigned char* Lb = smem + 8192;
            gld16(Atiles + g0 + lo, La + g0);
            gld16(Atiles + g1 + lo, La + g1);
            gld16(Btiles + g0 + lo, Lb + g0);
            gld16(Btiles + g1 + lo, Lb + g1);
        }

        const int rowOffA = (wv * 16 + ln) * 128;
        const int swz = ln & 7;
        int cur = 0;

        #pragma unroll 1
        for (int kb = 0; kb < 8; ++kb) {
            __syncthreads();   // buf 'cur' staged (vmcnt drain); prev reads done
            if (kb < 7) {
                const unsigned char* At = Atiles + (kb + 1) * 8192;
                const unsigned char* Bt = Btiles + (kb + 1) * 8192;
                unsigned char* La = smem + (cur ^ 1) * 16384;
                unsigned char* Lb = La + 8192;
                gld16(At + g0 + lo, La + g0);
                gld16(At + g1 + lo, La + g1);
                gld16(Bt + g0 + lo, Lb + g0);
                gld16(Bt + g1 + lo, Lb + g1);
            }
            const unsigned char* La = smem + cur * 16384;
            const unsigned char* Lb = La + 8192;
            #pragma unroll
            for (int ks = 0; ks < 2; ++ks) {
                const int ca = ((ks * 4 + quad) ^ swz) * 16;
                const short8 a = *(const short8*)(La + rowOffA + ca);
                #pragma unroll
                for (int t = 0; t < 4; ++t) {
                    const short8 b = *(const short8*)(Lb + (t * 16 + ln) * 128 + ca);
                    acc[t] = __builtin_amdgcn_mfma_f32_16x16x32_bf16(a, b, acc[t], 0, 0, 0);
                }
            }
            cur ^= 1;
        }

        // epilogue: bias + per-row Frobenius norm (C/D: col=lane&15, row=quad*4+i)
        const size_t drn = (size_t)2 * BATCH * 4096;
        const size_t din = drn + (size_t)BATCH * DDIM;
        const int woff = ct * 32;
        #pragma unroll
        for (int p = 0; p < 2; ++p) {
            const int colg = woff + p * 16 + ln;
            const float br = b_Dr[colg];
            const float bi = b_Di[colg];
            float dr[4], di[4], ps[4];
            #pragma unroll
            for (int i = 0; i < 4; ++i) {
                dr[i] = acc[2 * p][i] + br;
                di[i] = acc[2 * p + 1][i] + bi;
                ps[i] = dr[i] * dr[i] + di[i] * di[i];
            }
            #pragma unroll
            for (int i = 0; i < 4; ++i) {
                ps[i] += __shfl_xor(ps[i], 1);
                ps[i] += __shfl_xor(ps[i], 2);
                ps[i] += __shfl_xor(ps[i], 4);
                ps[i] += __shfl_xor(ps[i], 8);
            }
            #pragma unroll
            for (int i = 0; i < 4; ++i) {
                const float scale = 2.0f / sqrtf(8.0f * ps[i]);
                const size_t row_g = (size_t)(row0 + wv * 16 + quad * 4 + i);
                out[drn + row_g * DDIM + colg] = dr[i] * scale;
                out[din + row_g * DDIM + colg] = di[i] * scale;
            }
        }
    } else {
        // ---------------- diagonal patch ----------------
        const float* theta_ws = (const float*)(ws + THETA_OFF);
        const int pb   = bid - 512;            // 0..31
        const int b    = pb * 32 + (tid >> 3); // batch row
        const int tgrp = tid & 7;              // 8 antennas per thread

        const float4 t0 = *(const float4*)(theta_ws + b * NT + tgrp * 8);
        const float4 t1 = *(const float4*)(theta_ws + b * NT + tgrp * 8 + 4);
        const float th[8] = {t0.x, t0.y, t0.z, t0.w, t1.x, t1.y, t1.z, t1.w};

        float* ar = out + (size_t)b * 4096;
        float* ai = out + (size_t)BATCH * 4096 + (size_t)b * 4096;
        #pragma unroll
        for (int i = 0; i < 8; ++i) {
            const int t = tgrp * 8 + i;
            float s, c;
            sincosf(th[i], &s, &c);
            ar[t * 65] = c;
            ai[t * 65] = s;
        }
    }
}

extern "C" void kernel_launch(void* const* d_in, const int* in_sizes, int n_in,
                              void* d_out, int out_size, void* d_ws, size_t ws_size,
                              hipStream_t stream) {
    const float* x    = (const float*)d_in[0];
    const float* W_A  = (const float*)d_in[1];
    const float* b_A  = (const float*)d_in[2];
    const float* W_Dr = (const float*)d_in[3];
    const float* b_Dr = (const float*)d_in[4];
    const float* W_Di = (const float*)d_in[5];
    const float* b_Di = (const float*)d_in[6];
    const float* CSet = (const float*)d_in[7];
    float* out = (float*)d_out;
    unsigned char* ws = (unsigned char*)d_ws;

    // Zero the A_real/A_imag region (33.5 MB) via DMA memset node; diag
    // elements are patched by k1's patch blocks (stream-ordered after it).
    hipMemsetAsync(out, 0, (size_t)2 * BATCH * 4096 * sizeof(float), stream);

    k0_prep<<<288, 256, 0, stream>>>(x, W_A, b_A, W_Dr, W_Di, CSet, ws, out);
    k1_main<<<544, 256, 0, stream>>>(ws, b_Dr, b_Di, out);
}